// Round 6
// baseline (177.638 us; speedup 1.0000x reference)
//
#include <hip/hip_runtime.h>
#include <math.h>

// MHSA_27582279975470 — bf16/fp16 MFMA pipeline for MI355X (gfx950)
// B=4, C=256, NH=8, HD=32, H=W=64 -> Nq=4096, SR=2 -> Mkv=1024
//
// R6: (a) k_gemm_q deleted — q-projection fused into attn phase A (per-head
// q slice is block-local, zero redundancy; LDS roundtrip through Ks buffer).
// (b) k_gemm_kv: m-tile 64->32, grid (32,8,4)=1024 blocks = 4 blocks/CU,
// 16 waves/CU (was 2/8, occupancy+latency starved).

typedef __bf16 bf16;
typedef __attribute__((ext_vector_type(8))) __bf16 bf16x8;
typedef __attribute__((ext_vector_type(4))) float f32x4;
typedef __attribute__((ext_vector_type(4))) _Float16 f16x4;

#define MFMA16 __builtin_amdgcn_mfma_f32_16x16x32_bf16      // D[row=A-row][col=B-row]
#define MFMA16H __builtin_amdgcn_mfma_f32_16x16x16f16       // k=16, fp16 in

#define QSCALE 0.25503486f   // (1/sqrt(32)) * log2(e)
#define SOFTMAX_SHIFT 10.0f  // constant exp2-domain shift (softmax-invariant)

// ---------------------------------------------------------------- prep weights
__global__ void k_prep_w(const float* __restrict__ Wq, const float* __restrict__ Wk,
                         const float* __restrict__ Wv,
                         bf16* __restrict__ Wq_bf, bf16* __restrict__ Wkv_bf) {
    int idx = blockIdx.x * 256 + threadIdx.x;          // 0..65535
    Wq_bf[idx] = (bf16)(Wq[idx] * QSCALE);             // fold scale*log2e into q
#pragma unroll
    for (int r = 0; r < 8; r++) {
        int e = idx + r * 65536;                       // 0..524287
        int c = e >> 10, kk = e & 1023;                // c: 0..511 (k then v)
        int tap = kk >> 8, i = kk & 255;               // K-order: tap*256 + i
        const float* Wsrc = (c < 256) ? Wk : Wv;
        int cs = c & 255;
        // W[o][i][dy][dx] flat: o*1024 + i*4 + tap (tap = dy*2+dx)
        Wkv_bf[e] = (bf16)Wsrc[(cs * 256 + i) * 4 + tap];
    }
}

// ---------------------------------------------------------------- x transpose
__global__ void k_xT(const float* __restrict__ x, bf16* __restrict__ xT) {
    // grid (64 n-tiles, 4 c-tiles, 4 b), 256 thr, 64x64 tile
    int b = blockIdx.z, c0 = blockIdx.y * 64, n0 = blockIdx.x * 64;
    __shared__ float tile[64][65];
    int t = threadIdx.x;
    const float* xp = x + (size_t)(b * 256 + c0) * 4096 + n0;
#pragma unroll
    for (int k2 = 0; k2 < 16; k2++) {
        int flat = k2 * 256 + t;
        int row = flat >> 6, col = flat & 63;          // row = c-local, col = n-local
        tile[row][col] = xp[(size_t)row * 4096 + col];
    }
    __syncthreads();
    bf16* op = xT + (size_t)(b * 4096 + n0) * 256 + c0;
#pragma unroll
    for (int k2 = 0; k2 < 16; k2++) {
        int flat = k2 * 256 + t;
        int row = flat >> 6, col = flat & 63;          // row = n-local, col = c-local
        op[(size_t)row * 256 + col] = (bf16)tile[col][row];
    }
}

// ---------------------------------------------------------------- kv conv GEMM
// P-row fragments gathered directly from xT: P[m][k], k = tap*256+i maps to
// xT[n(m,tap)][i]; a 32-wide kk chunk stays within one tap.
__device__ inline void p_row_ptrs(const bf16* __restrict__ xb, int m, int lgofs,
                                  const bf16* __restrict__ p[4]) {
    int y = m >> 5, xw = m & 31;
    int nb = y * 128 + xw * 2;                         // top-left pixel of 2x2 patch
#pragma unroll
    for (int tap = 0; tap < 4; tap++) {
        int n = nb + (tap >> 1) * 64 + (tap & 1);
        p[tap] = xb + (size_t)n * 256 + lgofs;
    }
}
__device__ inline void c_row_ptrs(const bf16* __restrict__ row, int lgofs,
                                  const bf16* __restrict__ p[4]) {
#pragma unroll
    for (int tap = 0; tap < 4; tap++) p[tap] = row + tap * 256 + lgofs;
}

// Block tile: 32 m x 64 c, 4 waves; wave covers c-sub = w*16.
// zz<4 : kpos  D[m][c]  (A = P(xT) 2 frags, B = Wkv 1 frag)  + rel bias
// zz>=4: v     D[c][m]  (A = Wkv 1 frag, B = P(xT) 2 frags) -> fp16
__launch_bounds__(256)
__global__ void k_gemm_kv(const bf16* __restrict__ xT, const bf16* __restrict__ Wkv_bf,
                          const float* __restrict__ rel_h, const float* __restrict__ rel_w,
                          bf16* __restrict__ kpos_t, _Float16* __restrict__ v_td) {
    int b = blockIdx.z;
    int m0 = blockIdx.x * 32;
    int zz = blockIdx.y;
    bool vmode = zz >= 4;
    int c0 = (zz & 3) * 64;
    int t = threadIdx.x, l = t & 63, w = t >> 6;
    int lr = l & 15, lg = l >> 4;
    int lgofs = lg * 8;
    const bf16* xb = xT + (size_t)b * 4096 * 256;
    const bf16 *F0[4], *F1[4], *G0[4];   // F = 2-frag side, G = 1-frag side
    if (!vmode) {
        p_row_ptrs(xb, m0 + lr, lgofs, F0);            // A: P rows m
        p_row_ptrs(xb, m0 + 16 + lr, lgofs, F1);
        c_row_ptrs(Wkv_bf + (size_t)(c0 + w * 16 + lr) * 1024, lgofs, G0);  // B: W rows c
    } else {
        c_row_ptrs(Wkv_bf + (size_t)(256 + c0 + w * 16 + lr) * 1024, lgofs, G0); // A: W rows c
        p_row_ptrs(xb, m0 + lr, lgofs, F0);            // B: P rows m
        p_row_ptrs(xb, m0 + 16 + lr, lgofs, F1);
    }
    f32x4 acc[2] = {};
    if (!vmode) {
#pragma unroll
        for (int tap = 0; tap < 4; tap++)
#pragma unroll
            for (int j = 0; j < 8; j++) {
                int o = j * 32;
                bf16x8 a0 = *(const bf16x8*)(F0[tap] + o);
                bf16x8 a1 = *(const bf16x8*)(F1[tap] + o);
                bf16x8 b0 = *(const bf16x8*)(G0[tap] + o);
                acc[0] = MFMA16(a0, b0, acc[0], 0, 0, 0);
                acc[1] = MFMA16(a1, b0, acc[1], 0, 0, 0);
            }
        // acc[i]: row m = m0+i*16+lg*4+r, col c = c0+w*16+lr
        int cc = c0 + w * 16 + lr;
#pragma unroll
        for (int i = 0; i < 2; i++)
#pragma unroll
            for (int r = 0; r < 4; r++) {
                int m = m0 + i * 16 + lg * 4 + r;
                float val = acc[i][r] + rel_w[cc * 32 + (m >> 5)]
                                      + rel_h[cc * 32 + (m & 31)];
                kpos_t[((size_t)(b * 8 + (cc >> 5)) * 1024 + m) * 32 + (cc & 31)] = (bf16)val;
            }
    } else {
#pragma unroll
        for (int tap = 0; tap < 4; tap++)
#pragma unroll
            for (int j = 0; j < 8; j++) {
                int o = j * 32;
                bf16x8 a0 = *(const bf16x8*)(G0[tap] + o);
                bf16x8 b0 = *(const bf16x8*)(F0[tap] + o);
                bf16x8 b1 = *(const bf16x8*)(F1[tap] + o);
                acc[0] = MFMA16(a0, b0, acc[0], 0, 0, 0);
                acc[1] = MFMA16(a0, b1, acc[1], 0, 0, 0);
            }
        // acc[j]: row c = c0+w*16+lg*4+r, col m = m0+j*16+lr
#pragma unroll
        for (int j = 0; j < 2; j++) {
            int m = m0 + j * 16 + lr;
#pragma unroll
            for (int r = 0; r < 4; r++) {
                int cc = c0 + w * 16 + lg * 4 + r;
                v_td[((size_t)(b * 8 + (cc >> 5)) * 32 + (cc & 31)) * 1024 + m] = (_Float16)acc[j][r];
            }
        }
    }
}

// ---------------------------------------------------------------- attention (+q)
// Block = 4 waves x 32 queries = 128 q sharing K/V staged in LDS.
// Phase A: q = Wq·x for this wave's 32 n (frags from global, D-tiles ->
// wave-private LDS (reusing Ks) -> B-operand q-frags). Then 4 passes of 256 m:
// stage Ks[256][32] bf16 + Vs[32][264] f16; S^T = K·Q^T lands P in the
// 16x16x16 PV A-frag layout; softmax shift via MFMA C operand.
__launch_bounds__(256)
__global__ void k_attn(const bf16* __restrict__ xT, const bf16* __restrict__ Wq_bf,
                       const bf16* __restrict__ kpos_t, const _Float16* __restrict__ v_td,
                       float* __restrict__ out) {
    int b = blockIdx.z, h = blockIdx.y;
    int t = threadIdx.x;
    int w = t >> 6, l = t & 63;
    int n0 = blockIdx.x * 128 + w * 32;
    int lr = l & 15, lg = l >> 4;
    const size_t bh = (size_t)(b * 8 + h);
    __shared__ __align__(16) bf16 Ks[256 * 32];        // [m_local][d]; phase A: Qs
    __shared__ __align__(16) _Float16 Vs[32][264];     // [d][m_local], pad +8
    // ---- phase A: q[n][d] for n in [n0, n0+32), d in [0,32)
    bf16* Qs = Ks + w * 1024;                          // wave-private 32n x 32d
    {
        const bf16* Aw = Wq_bf + (size_t)(h * 32 + lr) * 256 + lg * 8;  // rows d
        const bf16* Bx = xT + (size_t)(b * 4096 + n0 + lr) * 256 + lg * 8; // rows n
        f32x4 aq[2][2] = {};
#pragma unroll
        for (int kk = 0; kk < 8; kk++) {
            bf16x8 a0 = *(const bf16x8*)(Aw + kk * 32);
            bf16x8 a1 = *(const bf16x8*)(Aw + 16 * 256 + kk * 32);
            bf16x8 b0 = *(const bf16x8*)(Bx + kk * 32);
            bf16x8 b1 = *(const bf16x8*)(Bx + 16 * 256 + kk * 32);
            aq[0][0] = MFMA16(a0, b0, aq[0][0], 0, 0, 0);
            aq[0][1] = MFMA16(a0, b1, aq[0][1], 0, 0, 0);
            aq[1][0] = MFMA16(a1, b0, aq[1][0], 0, 0, 0);
            aq[1][1] = MFMA16(a1, b1, aq[1][1], 0, 0, 0);
        }
        // D[row d = i*16+lg*4+r][col n = j*16+lr] -> Qs[n][d]
#pragma unroll
        for (int i = 0; i < 2; i++)
#pragma unroll
            for (int j = 0; j < 2; j++)
#pragma unroll
                for (int r = 0; r < 4; r++)
                    Qs[(j * 16 + lr) * 32 + i * 16 + lg * 4 + r] = (bf16)aq[i][j][r];
    }
    // same-wave LDS ops are ordered; read back B-operand q-frags
    bf16x8 bq0 = *(const bf16x8*)(Qs + lr * 32 + lg * 8);
    bf16x8 bq1 = *(const bf16x8*)(Qs + (16 + lr) * 32 + lg * 8);
    __syncthreads();   // all waves done with Qs before Ks staging clobbers it
    const bf16* Kb = kpos_t + bh * 1024 * 32;
    const _Float16* Vb = v_td + bh * 32 * 1024;
    f32x4 accO[2][2] = {};          // [n-half][d-tile]: col d = lr, row n = lg*4+r
    float ps0 = 0.f, ps1 = 0.f;     // per-lane row-sum partials (n = lr)
    const f32x4 zs = {-SOFTMAX_SHIFT, -SOFTMAX_SHIFT, -SOFTMAX_SHIFT, -SOFTMAX_SHIFT};
    for (int pass = 0; pass < 4; pass++) {
        // --- stage K chunk: rows [pass*256, +256) are 16KB contiguous
        const uint4* ksrc = (const uint4*)(Kb + (size_t)pass * 256 * 32);
        uint4* kdst = (uint4*)Ks;
#pragma unroll
        for (int j = 0; j < 4; j++) kdst[t + j * 256] = ksrc[t + j * 256];
        // --- stage V chunk: 32 rows x 512B segments -> padded LDS rows
#pragma unroll
        for (int j = 0; j < 4; j++) {
            int u = t + j * 256;                       // 0..1023 16B-units
            int row = u >> 5, col = u & 31;
            *(uint4*)(&Vs[row][col * 8]) =
                *(const uint4*)(Vb + (size_t)row * 1024 + pass * 256 + col * 8);
        }
        __syncthreads();
#pragma unroll 4
        for (int tt = 0; tt < 16; tt++) {
            // K as A-operand: A row i = m_local = tt*16+lr, k = d
            bf16x8 ak = *(const bf16x8*)(Ks + (tt * 16 + lr) * 32 + lg * 8);
            f32x4 s0 = MFMA16(ak, bq0, zs, 0, 0, 0);   // col n=lr, row m=tt*16+lg*4+r
            f32x4 s1 = MFMA16(ak, bq1, zs, 0, 0, 0);
            f16x4 p0, p1;
#pragma unroll
            for (int r = 0; r < 4; r++) {
                float e0 = fminf(__builtin_amdgcn_exp2f(s0[r]), 65504.f);
                float e1 = fminf(__builtin_amdgcn_exp2f(s1[r]), 65504.f);
                ps0 += e0; ps1 += e1;
                p0[r] = (_Float16)e0; p1[r] = (_Float16)e1;
            }
            // V as B-operand (k=16): B row j = d = lr, k = m_local = tt*16+lg*4+jj
            f16x4 v0 = *(const f16x4*)(&Vs[lr][tt * 16 + lg * 4]);
            f16x4 v1 = *(const f16x4*)(&Vs[16 + lr][tt * 16 + lg * 4]);
            accO[0][0] = MFMA16H(p0, v0, accO[0][0], 0, 0, 0);
            accO[0][1] = MFMA16H(p0, v1, accO[0][1], 0, 0, 0);
            accO[1][0] = MFMA16H(p1, v0, accO[1][0], 0, 0, 0);
            accO[1][1] = MFMA16H(p1, v1, accO[1][1], 0, 0, 0);
        }
        __syncthreads();
    }
    // row sums: lanes {lr, lr+16, lr+32, lr+48} hold disjoint m-partials
    ps0 += __shfl_xor(ps0, 16, 64); ps0 += __shfl_xor(ps0, 32, 64);
    ps1 += __shfl_xor(ps1, 16, 64); ps1 += __shfl_xor(ps1, 32, 64);
    float inv0[4], inv1[4];
#pragma unroll
    for (int r = 0; r < 4; r++) {
        inv0[r] = 1.0f / __shfl(ps0, lg * 4 + r, 64);
        inv1[r] = 1.0f / __shfl(ps1, lg * 4 + r, 64);
    }
#pragma unroll
    for (int dt = 0; dt < 2; dt++) {
        int c = h * 32 + dt * 16 + lr;     // accO col = d = lr
        float* op0 = out + (size_t)(b * 256 + c) * 4096 + n0 + lg * 4;
        float* op1 = op0 + 16;
        f32x4 o0, o1;
#pragma unroll
        for (int r = 0; r < 4; r++) {
            o0[r] = accO[0][dt][r] * inv0[r];
            o1[r] = accO[1][dt][r] * inv1[r];
        }
        *(f32x4*)op0 = o0;
        *(f32x4*)op1 = o1;
    }
}

// ---------------------------------------------------------------- launcher
extern "C" void kernel_launch(void* const* d_in, const int* in_sizes, int n_in,
                              void* d_out, int out_size, void* d_ws, size_t ws_size,
                              hipStream_t stream) {
    const float* x    = (const float*)d_in[0];
    const float* Wq   = (const float*)d_in[1];
    const float* Wk   = (const float*)d_in[2];
    const float* Wv   = (const float*)d_in[3];
    const float* relh = (const float*)d_in[4];
    const float* relw = (const float*)d_in[5];
    float* out = (float*)d_out;
    char* ws = (char*)d_ws;

    bf16*      xT     = (bf16*)(ws);                                  // 8 MiB
    bf16*      kposT  = (bf16*)(ws + (8u << 20));                     // 2 MiB
    _Float16*  v_td   = (_Float16*)(ws + (10u << 20));                // 2 MiB
    bf16*      Wq_bf  = (bf16*)(ws + (12u << 20));                    // 128 KiB
    bf16*      Wkv_bf = (bf16*)(ws + (12u << 20) + (256u << 10));     // 1 MiB

    k_prep_w <<<256,            256, 0, stream>>>(Wq, Wk, Wv, Wq_bf, Wkv_bf);
    k_xT     <<<dim3(64, 4, 4), 256, 0, stream>>>(x, xT);
    k_gemm_kv<<<dim3(32, 8, 4), 256, 0, stream>>>(xT, Wkv_bf, relh, relw, kposT, v_td);
    k_attn   <<<dim3(32, 8, 4), 256, 0, stream>>>(xT, Wq_bf, kposT, v_td, out);
}

// Round 7
// 173.606 us; speedup vs baseline: 1.0232x; 1.0232x over previous
//
#include <hip/hip_runtime.h>
#include <math.h>

// MHSA_27582279975470 — bf16/fp16 MFMA pipeline for MI355X (gfx950)
// B=4, C=256, NH=8, HD=32, H=W=64 -> Nq=4096, SR=2 -> Mkv=1024
//
// R7: (a) attn phase-A Qs: stride 40 + packed b64 stores (kills the 3.6M
// bank-conflict cycles R6 introduced); (b) attn K/V staging reg-prefetch
// double-step (global latency hides under MFMAs); (c) gemm_kv: one block
// computes BOTH kpos and v for 32m x 64c, P rows staged in LDS dbuf ->
// P global traffic 256MB -> 32MB; (d) prep_w fully coalesced.

typedef __bf16 bf16;
typedef __attribute__((ext_vector_type(4))) __bf16 bf16x4;
typedef __attribute__((ext_vector_type(8))) __bf16 bf16x8;
typedef __attribute__((ext_vector_type(4))) float f32x4;
typedef __attribute__((ext_vector_type(4))) _Float16 f16x4;

#define MFMA16 __builtin_amdgcn_mfma_f32_16x16x32_bf16      // D[row=A-row][col=B-row]
#define MFMA16H __builtin_amdgcn_mfma_f32_16x16x16f16       // k=16, fp16 in

#define QSCALE 0.25503486f   // (1/sqrt(32)) * log2(e)
#define SOFTMAX_SHIFT 10.0f  // constant exp2-domain shift (softmax-invariant)

// ---------------------------------------------------------------- prep weights
// Coalesced: float4 reads (one 2x2 tap-quad / one Wq quad), contiguous writes.
__global__ void k_prep_w(const float* __restrict__ Wq, const float* __restrict__ Wk,
                         const float* __restrict__ Wv,
                         bf16* __restrict__ Wq_bf, bf16* __restrict__ Wkv_bf) {
    int tid = blockIdx.x * 256 + threadIdx.x;          // 0..131071
    int c = tid >> 8, i = tid & 255;                   // c: 0..511 (k then v)
    const float* Wsrc = (c < 256) ? Wk : Wv;
    int cs = c & 255;
    f32x4 w4 = ((const f32x4*)Wsrc)[cs * 256 + i];     // W[c][i][0..3], 16B
#pragma unroll
    for (int tap = 0; tap < 4; tap++)                  // K-order: tap*256 + i
        Wkv_bf[c * 1024 + tap * 256 + i] = (bf16)w4[tap];
    if (tid < 16384) {
        f32x4 q4 = ((const f32x4*)Wq)[tid];
        bf16x4 o;
#pragma unroll
        for (int e = 0; e < 4; e++) o[e] = (bf16)(q4[e] * QSCALE);
        *(bf16x4*)(Wq_bf + tid * 4) = o;               // fold scale*log2e into q
    }
}

// ---------------------------------------------------------------- x transpose
__global__ void k_xT(const float* __restrict__ x, bf16* __restrict__ xT) {
    // grid (64 n-tiles, 4 c-tiles, 4 b), 256 thr, 64x64 tile
    int b = blockIdx.z, c0 = blockIdx.y * 64, n0 = blockIdx.x * 64;
    __shared__ float tile[64][65];
    int t = threadIdx.x;
    const float* xp = x + (size_t)(b * 256 + c0) * 4096 + n0;
#pragma unroll
    for (int k2 = 0; k2 < 16; k2++) {
        int flat = k2 * 256 + t;
        int row = flat >> 6, col = flat & 63;          // row = c-local, col = n-local
        tile[row][col] = xp[(size_t)row * 4096 + col];
    }
    __syncthreads();
    bf16* op = xT + (size_t)(b * 4096 + n0) * 256 + c0;
#pragma unroll
    for (int k2 = 0; k2 < 16; k2++) {
        int flat = k2 * 256 + t;
        int row = flat >> 6, col = flat & 63;          // row = n-local, col = c-local
        op[(size_t)row * 256 + col] = (bf16)tile[col][row];
    }
}

// ---------------------------------------------------------------- kv conv GEMM
// Block = 32 m x 64 c, computes BOTH kpos and v (P-frags shared between the
// two GEMMs). P rows staged in LDS (dbuf 2x16.5KB, reg-prefetch); each chunk
// = one tap (256 k). Weights read from global (1MB, L2-resident).
// Accumulation order (tap-major, 32-wide) identical to R6 -> same bits.
__launch_bounds__(256)
__global__ void k_gemm_kv(const bf16* __restrict__ xT, const bf16* __restrict__ Wkv_bf,
                          const float* __restrict__ rel_h, const float* __restrict__ rel_w,
                          bf16* __restrict__ kpos_t, _Float16* __restrict__ v_td) {
    int b = blockIdx.z;
    int bx = blockIdx.x;                               // m-tile: m0 = bx*32, y = bx
    int m0 = bx * 32;
    int c0w = blockIdx.y * 64 + (threadIdx.x >> 6) * 16;
    int t = threadIdx.x, l = t & 63;
    int lr = l & 15, lg = l >> 4;
    __shared__ __align__(16) bf16 Ps[2][32 * 264];     // row stride 264 (+8 pad)
    const bf16* xb = xT + (size_t)b * 4096 * 256;
    // staging geometry: unit u (16B) -> row = u>>5, cu = u&31
    int srow = t >> 3;                                 // 4 units/thread: rows t>>3
    int scu0 = (t & 7) * 4;                            // cols (t&7)*4 .. +3
    uint4 pre[4];
    // n(row, tap) with y = bx: n = (2bx+dy)*64 + 2*row + dx
#define LOAD_CHUNK(tap)                                                        \
    {                                                                          \
        int dy = (tap) >> 1, dx = (tap) & 1;                                   \
        const bf16* src = xb + (size_t)((2 * bx + dy) * 64 + 2 * srow + dx) * 256; \
        _Pragma("unroll")                                                      \
        for (int j = 0; j < 4; j++)                                            \
            pre[j] = *(const uint4*)(src + (scu0 + j) * 8);                    \
    }
#define WRITE_CHUNK(buf)                                                       \
    {                                                                          \
        bf16* dst = Ps[buf] + srow * 264 + scu0 * 8;                           \
        _Pragma("unroll")                                                      \
        for (int j = 0; j < 4; j++) *(uint4*)(dst + j * 8) = pre[j];           \
    }
    LOAD_CHUNK(0)
    WRITE_CHUNK(0)
    const bf16* Gkb = Wkv_bf + (size_t)(c0w + lr) * 1024 + lg * 8;
    const bf16* Gvb = Gkb + 256 * 1024;
    f32x4 accK[2] = {}, accV[2] = {};
    for (int ch = 0; ch < 4; ch++) {
        if (ch < 3) LOAD_CHUNK(ch + 1)
        __syncthreads();
        const bf16* P = Ps[ch & 1];
#pragma unroll
        for (int kk = 0; kk < 8; kk++) {
            bf16x8 pa0 = *(const bf16x8*)(P + lr * 264 + kk * 32 + lg * 8);
            bf16x8 pa1 = *(const bf16x8*)(P + (16 + lr) * 264 + kk * 32 + lg * 8);
            bf16x8 gk = *(const bf16x8*)(Gkb + ch * 256 + kk * 32);
            bf16x8 gv = *(const bf16x8*)(Gvb + ch * 256 + kk * 32);
            accK[0] = MFMA16(pa0, gk, accK[0], 0, 0, 0);
            accK[1] = MFMA16(pa1, gk, accK[1], 0, 0, 0);
            accV[0] = MFMA16(gv, pa0, accV[0], 0, 0, 0);
            accV[1] = MFMA16(gv, pa1, accV[1], 0, 0, 0);
        }
        if (ch < 3) {
            __syncthreads();
            WRITE_CHUNK((ch + 1) & 1)
        }
    }
    // kpos: accK[i] row m = m0+i*16+lg*4+r, col c = c0w+lr
    {
        int cc = c0w + lr;
        float rw = rel_w[cc * 32 + bx];                // y = bx for whole block
#pragma unroll
        for (int i = 0; i < 2; i++)
#pragma unroll
            for (int r = 0; r < 4; r++) {
                int ml = i * 16 + lg * 4 + r;          // m&31
                float val = accK[i][r] + rw + rel_h[cc * 32 + ml];
                kpos_t[((size_t)(b * 8 + (cc >> 5)) * 1024 + m0 + ml) * 32 + (cc & 31)] = (bf16)val;
            }
    }
    // v: accV[j] row c = c0w+lg*4+r, col m = m0+j*16+lr
#pragma unroll
    for (int j = 0; j < 2; j++) {
        int m = m0 + j * 16 + lr;
#pragma unroll
        for (int r = 0; r < 4; r++) {
            int cc = c0w + lg * 4 + r;
            v_td[((size_t)(b * 8 + (cc >> 5)) * 32 + (cc & 31)) * 1024 + m] = (_Float16)accV[j][r];
        }
    }
#undef LOAD_CHUNK
#undef WRITE_CHUNK
}

// ---------------------------------------------------------------- attention (+q)
// Block = 4 waves x 32 queries = 128 q sharing K/V staged in LDS.
// Phase A: q = Wq·x (frags from global; D -> wave-private padded Qs, packed
// b64 stores -> conflict-free) -> B-operand q-frags. Then 4 passes of 256 m
// with reg-prefetch staging (loads for pass+1 fly under pass's MFMAs).
__launch_bounds__(256)
__global__ void k_attn(const bf16* __restrict__ xT, const bf16* __restrict__ Wq_bf,
                       const bf16* __restrict__ kpos_t, const _Float16* __restrict__ v_td,
                       float* __restrict__ out) {
    int b = blockIdx.z, h = blockIdx.y;
    int t = threadIdx.x;
    int w = t >> 6, l = t & 63;
    int n0 = blockIdx.x * 128 + w * 32;
    int lr = l & 15, lg = l >> 4;
    const size_t bh = (size_t)(b * 8 + h);
    __shared__ __align__(16) bf16 Ks[256 * 32];        // [m_local][d]; phase A: Qs
    __shared__ __align__(16) _Float16 Vs[32][264];     // [d][m_local], pad +8
    const bf16* Kb = kpos_t + bh * 1024 * 32;
    const _Float16* Vb = v_td + bh * 32 * 1024;
    // prefetch pass-0 K/V while phase A computes
    uint4 kpre[4], vpre[4];
#define LOAD_PASS(pass)                                                        \
    {                                                                          \
        const uint4* ksrc = (const uint4*)(Kb + (size_t)(pass) * 256 * 32);    \
        _Pragma("unroll")                                                      \
        for (int j = 0; j < 4; j++) kpre[j] = ksrc[t + j * 256];               \
        _Pragma("unroll")                                                      \
        for (int j = 0; j < 4; j++) {                                          \
            int u = t + j * 256;                                               \
            vpre[j] = *(const uint4*)(Vb + (size_t)(u >> 5) * 1024 +           \
                                      (pass) * 256 + (u & 31) * 8);            \
        }                                                                      \
    }
#define WRITE_PASS()                                                           \
    {                                                                          \
        uint4* kdst = (uint4*)Ks;                                              \
        _Pragma("unroll")                                                      \
        for (int j = 0; j < 4; j++) kdst[t + j * 256] = kpre[j];               \
        _Pragma("unroll")                                                      \
        for (int j = 0; j < 4; j++) {                                          \
            int u = t + j * 256;                                               \
            *(uint4*)(&Vs[u >> 5][(u & 31) * 8]) = vpre[j];                    \
        }                                                                      \
    }
    LOAD_PASS(0)
    // ---- phase A: q[n][d], n in [n0,n0+32), d in [0,32); Qs stride 40
    bf16* Qs = Ks + w * 1280;                          // wave-private 32n x 40
    {
        const bf16* Aw = Wq_bf + (size_t)(h * 32 + lr) * 256 + lg * 8;     // rows d
        const bf16* Bx = xT + (size_t)(b * 4096 + n0 + lr) * 256 + lg * 8; // rows n
        f32x4 aq[2][2] = {};
#pragma unroll
        for (int kk = 0; kk < 8; kk++) {
            bf16x8 a0 = *(const bf16x8*)(Aw + kk * 32);
            bf16x8 a1 = *(const bf16x8*)(Aw + 16 * 256 + kk * 32);
            bf16x8 b0 = *(const bf16x8*)(Bx + kk * 32);
            bf16x8 b1 = *(const bf16x8*)(Bx + 16 * 256 + kk * 32);
            aq[0][0] = MFMA16(a0, b0, aq[0][0], 0, 0, 0);
            aq[0][1] = MFMA16(a0, b1, aq[0][1], 0, 0, 0);
            aq[1][0] = MFMA16(a1, b0, aq[1][0], 0, 0, 0);
            aq[1][1] = MFMA16(a1, b1, aq[1][1], 0, 0, 0);
        }
        // D[row d = i*16+lg*4+r][col n = j*16+lr] -> Qs[n*40 + d], packed b64
#pragma unroll
        for (int i = 0; i < 2; i++)
#pragma unroll
            for (int j = 0; j < 2; j++) {
                bf16x4 pk;
#pragma unroll
                for (int r = 0; r < 4; r++) pk[r] = (bf16)aq[i][j][r];
                *(bf16x4*)(Qs + (j * 16 + lr) * 40 + i * 16 + lg * 4) = pk;
            }
    }
    // same-wave readback (b64 pairs; 80B rows are 8B-aligned, ~2-way banks)
    bf16x8 bq0, bq1;
    {
        bf16x4 a0 = *(const bf16x4*)(Qs + lr * 40 + lg * 8);
        bf16x4 a1 = *(const bf16x4*)(Qs + lr * 40 + lg * 8 + 4);
        bf16x4 b0 = *(const bf16x4*)(Qs + (16 + lr) * 40 + lg * 8);
        bf16x4 b1 = *(const bf16x4*)(Qs + (16 + lr) * 40 + lg * 8 + 4);
#pragma unroll
        for (int e = 0; e < 4; e++) {
            bq0[e] = a0[e]; bq0[4 + e] = a1[e];
            bq1[e] = b0[e]; bq1[4 + e] = b1[e];
        }
    }
    __syncthreads();   // all waves done with Qs before staging clobbers Ks
    WRITE_PASS()
    f32x4 accO[2][2] = {};          // [n-half][d-tile]: col d = lr, row n = lg*4+r
    float ps0 = 0.f, ps1 = 0.f;     // per-lane row-sum partials (n = lr)
    const f32x4 zs = {-SOFTMAX_SHIFT, -SOFTMAX_SHIFT, -SOFTMAX_SHIFT, -SOFTMAX_SHIFT};
    for (int pass = 0; pass < 4; pass++) {
        if (pass < 3) LOAD_PASS(pass + 1)              // fly under this pass's MFMAs
        __syncthreads();                               // staging of `pass` visible
#pragma unroll 4
        for (int tt = 0; tt < 16; tt++) {
            // K as A-operand: A row i = m_local = tt*16+lr, k = d
            bf16x8 ak = *(const bf16x8*)(Ks + (tt * 16 + lr) * 32 + lg * 8);
            f32x4 s0 = MFMA16(ak, bq0, zs, 0, 0, 0);   // col n=lr, row m=tt*16+lg*4+r
            f32x4 s1 = MFMA16(ak, bq1, zs, 0, 0, 0);
            f16x4 p0, p1;
#pragma unroll
            for (int r = 0; r < 4; r++) {
                float e0 = fminf(__builtin_amdgcn_exp2f(s0[r]), 65504.f);
                float e1 = fminf(__builtin_amdgcn_exp2f(s1[r]), 65504.f);
                ps0 += e0; ps1 += e1;
                p0[r] = (_Float16)e0; p1[r] = (_Float16)e1;
            }
            // V as B-operand (k=16): B row j = d = lr, k = m_local = tt*16+lg*4+jj
            f16x4 v0 = *(const f16x4*)(&Vs[lr][tt * 16 + lg * 4]);
            f16x4 v1 = *(const f16x4*)(&Vs[16 + lr][tt * 16 + lg * 4]);
            accO[0][0] = MFMA16H(p0, v0, accO[0][0], 0, 0, 0);
            accO[0][1] = MFMA16H(p0, v1, accO[0][1], 0, 0, 0);
            accO[1][0] = MFMA16H(p1, v0, accO[1][0], 0, 0, 0);
            accO[1][1] = MFMA16H(p1, v1, accO[1][1], 0, 0, 0);
        }
        if (pass < 3) {
            __syncthreads();                           // all waves done reading
            WRITE_PASS()
        }
    }
#undef LOAD_PASS
#undef WRITE_PASS
    // row sums: lanes {lr, lr+16, lr+32, lr+48} hold disjoint m-partials
    ps0 += __shfl_xor(ps0, 16, 64); ps0 += __shfl_xor(ps0, 32, 64);
    ps1 += __shfl_xor(ps1, 16, 64); ps1 += __shfl_xor(ps1, 32, 64);
    float inv0[4], inv1[4];
#pragma unroll
    for (int r = 0; r < 4; r++) {
        inv0[r] = 1.0f / __shfl(ps0, lg * 4 + r, 64);
        inv1[r] = 1.0f / __shfl(ps1, lg * 4 + r, 64);
    }
#pragma unroll
    for (int dt = 0; dt < 2; dt++) {
        int c = h * 32 + dt * 16 + lr;     // accO col = d = lr
        float* op0 = out + (size_t)(b * 256 + c) * 4096 + n0 + lg * 4;
        float* op1 = op0 + 16;
        f32x4 o0, o1;
#pragma unroll
        for (int r = 0; r < 4; r++) {
            o0[r] = accO[0][dt][r] * inv0[r];
            o1[r] = accO[1][dt][r] * inv1[r];
        }
        *(f32x4*)op0 = o0;
        *(f32x4*)op1 = o1;
    }
}

// ---------------------------------------------------------------- launcher
extern "C" void kernel_launch(void* const* d_in, const int* in_sizes, int n_in,
                              void* d_out, int out_size, void* d_ws, size_t ws_size,
                              hipStream_t stream) {
    const float* x    = (const float*)d_in[0];
    const float* Wq   = (const float*)d_in[1];
    const float* Wk   = (const float*)d_in[2];
    const float* Wv   = (const float*)d_in[3];
    const float* relh = (const float*)d_in[4];
    const float* relw = (const float*)d_in[5];
    float* out = (float*)d_out;
    char* ws = (char*)d_ws;

    bf16*      xT     = (bf16*)(ws);                                  // 8 MiB
    bf16*      kposT  = (bf16*)(ws + (8u << 20));                     // 2 MiB
    _Float16*  v_td   = (_Float16*)(ws + (10u << 20));                // 2 MiB
    bf16*      Wq_bf  = (bf16*)(ws + (12u << 20));                    // 128 KiB
    bf16*      Wkv_bf = (bf16*)(ws + (12u << 20) + (256u << 10));     // 1 MiB

    k_prep_w <<<512,            256, 0, stream>>>(Wq, Wk, Wv, Wq_bf, Wkv_bf);
    k_xT     <<<dim3(64, 4, 4), 256, 0, stream>>>(x, xT);
    k_gemm_kv<<<dim3(32, 4, 4), 256, 0, stream>>>(xT, Wkv_bf, relh, relw, kposT, v_td);
    k_attn   <<<dim3(32, 8, 4), 256, 0, stream>>>(xT, Wq_bf, kposT, v_td, out);
}